// Round 12
// baseline (45.983 us; speedup 1.0000x reference)
//
#include <hip/hip_runtime.h>

// Problem dims (fixed by the reference)
#define BB 2
#define LL 1024
#define DI 1536
#define DS 16
#define TPB 256

#define LOG2E 1.44269504088896340736f

__device__ __forceinline__ float exp2_fast(float x) { return __builtin_amdgcn_exp2f(x); }

// ---------------------------------------------------------------------------
// Pass 1: thread <-> (b, d, chunk); all 16 n-states in registers.
// B tile [CL][16] staged via LDS (one coalesced load), per-step access is an
// all-lanes-same-address ds_read_b128 broadcast (no per-step global loads).
// Stores per-chunk: sdt = sum(delta) and Bacc[n]:
//   x_after = exp2(Av2[n]*sdt)*x_before + Bacc[n]
// Layouts: sdt [c][b][d], bsum [c][b][d][n] (n-minor; float4-vectorized I/O)
// ---------------------------------------------------------------------------
template <int NCc>
__global__ __launch_bounds__(TPB) void ss1(
    const float* __restrict__ u, const float* __restrict__ delta,
    const float* __restrict__ A, const float* __restrict__ Bm,
    float* __restrict__ sdt_out, float* __restrict__ bsum)
{
    constexpr int CLc = LL / NCc;
    __shared__ float bsh[CLc * DS];

    const int tid = threadIdx.x;
    const int d = blockIdx.x * TPB + tid;
    const int c = blockIdx.y;
    const int b = blockIdx.z;

    const size_t bl0 = (size_t)b * LL + (size_t)c * CLc;

    // Stage B tile: CL*DS consecutive floats, one coalesced load.
    {
        const float* __restrict__ bp0 = Bm + bl0 * DS;
        if (tid < CLc * DS) bsh[tid] = bp0[tid];
    }

    float Av2[DS];
    {
        const float4* Ap = (const float4*)(A + (size_t)d * DS);
        #pragma unroll
        for (int q = 0; q < 4; ++q) {
            const float4 av = Ap[q];
            Av2[q*4+0] = av.x * LOG2E; Av2[q*4+1] = av.y * LOG2E;
            Av2[q*4+2] = av.z * LOG2E; Av2[q*4+3] = av.w * LOG2E;
        }
    }

    const float* __restrict__ dp = delta + bl0 * DI + d;
    const float* __restrict__ up = u     + bl0 * DI + d;

    float dt[CLc], uu[CLc];
    #pragma unroll
    for (int i = 0; i < CLc; ++i) {
        dt[i] = dp[(size_t)i * DI];          // coalesced 256B/wave
        uu[i] = up[(size_t)i * DI];
    }

    __syncthreads();

    float Bacc[DS];
    #pragma unroll
    for (int n = 0; n < DS; ++n) Bacc[n] = 0.0f;
    float sdt = 0.0f;

    #pragma unroll
    for (int i = 0; i < CLc; ++i) {
        const float du = dt[i] * uu[i];
        sdt += dt[i];
        const float4* bt4 = (const float4*)(bsh + i * DS);   // LDS broadcast
        const float4 b0 = bt4[0], b1 = bt4[1], b2 = bt4[2], b3 = bt4[3];
        const float bv[DS] = {b0.x,b0.y,b0.z,b0.w, b1.x,b1.y,b1.z,b1.w,
                              b2.x,b2.y,b2.z,b2.w, b3.x,b3.y,b3.z,b3.w};
        #pragma unroll
        for (int n = 0; n < DS; ++n) {
            const float a = exp2_fast(dt[i] * Av2[n]);
            Bacc[n] = fmaf(a, Bacc[n], du * bv[n]);
        }
    }

    sdt_out[((size_t)c * BB + b) * DI + d] = sdt;
    float4* __restrict__ sp = (float4*)(bsum + (((size_t)c * BB + b) * DI + d) * DS);
    #pragma unroll
    for (int q = 0; q < 4; ++q)
        sp[q] = make_float4(Bacc[q*4+0], Bacc[q*4+1], Bacc[q*4+2], Bacc[q*4+3]);
}

// ---------------------------------------------------------------------------
// Pass 1.5: exclusive scan over chunks per (b,d,n) chain (round-3 proven).
// ---------------------------------------------------------------------------
template <int NCc>
__global__ __launch_bounds__(TPB) void ss_scan(
    const float* __restrict__ A,
    const float* __restrict__ sdt_in, const float* __restrict__ bsum,
    float* __restrict__ xin)
{
    const int gid = blockIdx.x * TPB + threadIdx.x;   // (b*DI+d)*DS+n
    const int bd  = gid >> 4;
    const int d   = bd % DI;
    const int n   = gid & 15;
    const float Av2 = A[d * DS + n] * LOG2E;

    const size_t cstr = (size_t)BB * DI * DS;
    const size_t sstr = (size_t)BB * DI;

    float x = 0.0f;
    #pragma unroll 8
    for (int c = 0; c < NCc; ++c) {
        xin[(size_t)c * cstr + gid] = x;               // state BEFORE chunk c
        const float a = exp2_fast(Av2 * sdt_in[(size_t)c * sstr + bd]);
        x = fmaf(a, x, bsum[(size_t)c * cstr + gid]);
    }
}

// ---------------------------------------------------------------------------
// Pass 2: thread <-> (b, d, chunk); B and C tiles staged via LDS; load
// incoming state (float4), re-run chunk, reduce over n in regs, write y.
// ---------------------------------------------------------------------------
template <int NCc>
__global__ __launch_bounds__(TPB) void ss2(
    const float* __restrict__ u, const float* __restrict__ delta,
    const float* __restrict__ A, const float* __restrict__ Bm,
    const float* __restrict__ Cm, const float* __restrict__ Dv,
    const float* __restrict__ xin, float* __restrict__ y)
{
    constexpr int CLc = LL / NCc;
    __shared__ float bsh[CLc * DS];
    __shared__ float csh[CLc * DS];

    const int tid = threadIdx.x;
    const int d = blockIdx.x * TPB + tid;
    const int c = blockIdx.y;
    const int b = blockIdx.z;

    const size_t bl0 = (size_t)b * LL + (size_t)c * CLc;

    // Stage B and C tiles (one coalesced load each).
    {
        const float* __restrict__ bp0 = Bm + bl0 * DS;
        const float* __restrict__ cp0 = Cm + bl0 * DS;
        if (tid < CLc * DS) {
            bsh[tid] = bp0[tid];
            csh[tid] = cp0[tid];
        }
    }

    float Av2[DS];
    {
        const float4* Ap = (const float4*)(A + (size_t)d * DS);
        #pragma unroll
        for (int q = 0; q < 4; ++q) {
            const float4 av = Ap[q];
            Av2[q*4+0] = av.x * LOG2E; Av2[q*4+1] = av.y * LOG2E;
            Av2[q*4+2] = av.z * LOG2E; Av2[q*4+3] = av.w * LOG2E;
        }
    }

    float x[DS];
    {
        const float4* __restrict__ xp =
            (const float4*)(xin + (((size_t)c * BB + b) * DI + d) * DS);
        #pragma unroll
        for (int q = 0; q < 4; ++q) {
            const float4 v = xp[q];
            x[q*4+0] = v.x; x[q*4+1] = v.y; x[q*4+2] = v.z; x[q*4+3] = v.w;
        }
    }

    const float Dd = Dv[d];

    const float* __restrict__ dp = delta + bl0 * DI + d;
    const float* __restrict__ up = u     + bl0 * DI + d;
    float* __restrict__ yp       = y     + bl0 * DI + d;

    float dt[CLc], uu[CLc];
    #pragma unroll
    for (int i = 0; i < CLc; ++i) {
        dt[i] = dp[(size_t)i * DI];
        uu[i] = up[(size_t)i * DI];
    }

    __syncthreads();

    #pragma unroll
    for (int i = 0; i < CLc; ++i) {
        const float du = dt[i] * uu[i];
        const float4* bt4 = (const float4*)(bsh + i * DS);   // LDS broadcast
        const float4* ct4 = (const float4*)(csh + i * DS);
        const float4 b0 = bt4[0], b1 = bt4[1], b2 = bt4[2], b3 = bt4[3];
        const float4 c0 = ct4[0], c1 = ct4[1], c2 = ct4[2], c3 = ct4[3];
        const float bv[DS] = {b0.x,b0.y,b0.z,b0.w, b1.x,b1.y,b1.z,b1.w,
                              b2.x,b2.y,b2.z,b2.w, b3.x,b3.y,b3.z,b3.w};
        const float cv[DS] = {c0.x,c0.y,c0.z,c0.w, c1.x,c1.y,c1.z,c1.w,
                              c2.x,c2.y,c2.z,c2.w, c3.x,c3.y,c3.z,c3.w};
        float y0 = 0.0f, y1 = 0.0f;
        #pragma unroll
        for (int n = 0; n < DS; ++n) {
            const float a = exp2_fast(dt[i] * Av2[n]);
            x[n] = fmaf(a, x[n], du * bv[n]);
            if (n & 1) y1 = fmaf(x[n], cv[n], y1);
            else       y0 = fmaf(x[n], cv[n], y0);
        }
        yp[(size_t)i * DI] = fmaf(uu[i], Dd, y0 + y1);
    }
}

// Fallback: streaming serial scan (no workspace needed)
__global__ __launch_bounds__(TPB) void ss_serial(
    const float* __restrict__ u, const float* __restrict__ delta,
    const float* __restrict__ A, const float* __restrict__ Bm,
    const float* __restrict__ Cm, const float* __restrict__ Dv,
    float* __restrict__ y)
{
    const int d = blockIdx.x * TPB + threadIdx.x;
    const int b = blockIdx.z;

    float Av2[DS];
    #pragma unroll
    for (int n = 0; n < DS; ++n) Av2[n] = A[d * DS + n] * LOG2E;

    float x[DS];
    #pragma unroll
    for (int n = 0; n < DS; ++n) x[n] = 0.0f;

    const float Dd = Dv[d];
    const size_t bl0 = (size_t)b * LL;
    const float* __restrict__ dp = delta + bl0 * DI + d;
    const float* __restrict__ up = u     + bl0 * DI + d;
    const float* __restrict__ bp = Bm    + bl0 * DS;
    const float* __restrict__ cp = Cm    + bl0 * DS;
    float* __restrict__ yp       = y     + bl0 * DI + d;

    for (int t = 0; t < LL; ++t) {
        const float dtv = dp[(size_t)t * DI];
        const float uuv = up[(size_t)t * DI];
        const float du = dtv * uuv;
        const float* __restrict__ bt = bp + t * DS;
        const float* __restrict__ ct = cp + t * DS;
        float y0 = 0.0f, y1 = 0.0f;
        #pragma unroll
        for (int n = 0; n < DS; ++n) {
            const float a = exp2_fast(dtv * Av2[n]);
            x[n] = fmaf(a, x[n], du * bt[n]);
            if (n & 1) y1 = fmaf(x[n], ct[n], y1);
            else       y0 = fmaf(x[n], ct[n], y0);
        }
        yp[(size_t)t * DI] = fmaf(uuv, Dd, y0 + y1);
    }
}

template <int NCc>
static void launch_chunked(const float* u, const float* delta, const float* A,
                           const float* Bm, const float* Cm, const float* Dv,
                           float* y, void* d_ws, hipStream_t stream) {
    const size_t sdt_bytes  = (size_t)NCc * BB * DI * sizeof(float);
    const size_t bsum_bytes = (size_t)NCc * BB * DI * DS * sizeof(float);

    float* sdt  = (float*)d_ws;
    float* bsum = (float*)((char*)d_ws + sdt_bytes);
    float* xin  = (float*)((char*)d_ws + sdt_bytes + bsum_bytes);

    dim3 grid1(DI / TPB, NCc, BB);
    ss1<NCc><<<grid1, TPB, 0, stream>>>(u, delta, A, Bm, sdt, bsum);

    dim3 gridS((BB * DI * DS) / TPB, 1, 1);
    ss_scan<NCc><<<gridS, TPB, 0, stream>>>(A, sdt, bsum, xin);

    ss2<NCc><<<grid1, TPB, 0, stream>>>(u, delta, A, Bm, Cm, Dv, xin, y);
}

extern "C" void kernel_launch(void* const* d_in, const int* in_sizes, int n_in,
                              void* d_out, int out_size, void* d_ws, size_t ws_size,
                              hipStream_t stream) {
    const float* u     = (const float*)d_in[0];
    const float* delta = (const float*)d_in[1];
    const float* A     = (const float*)d_in[2];
    const float* Bm    = (const float*)d_in[3];
    const float* Cm    = (const float*)d_in[4];
    const float* Dv    = (const float*)d_in[5];
    float* y = (float*)d_out;

    auto need = [](int nc) {
        return (size_t)nc * BB * DI * sizeof(float) +            // sdt
               2 * (size_t)nc * BB * DI * DS * sizeof(float);    // bsum + xin
    };

    if (ws_size >= need(128)) {
        launch_chunked<128>(u, delta, A, Bm, Cm, Dv, y, d_ws, stream);
    } else if (ws_size >= need(64)) {
        launch_chunked<64>(u, delta, A, Bm, Cm, Dv, y, d_ws, stream);
    } else {
        dim3 grid(DI / TPB, 1, BB);
        ss_serial<<<grid, TPB, 0, stream>>>(u, delta, A, Bm, Cm, Dv, y);
    }
}

// Round 13
// 38.599 us; speedup vs baseline: 1.1913x; 1.1913x over previous
//
#include <hip/hip_runtime.h>

// Problem dims (fixed by the reference)
#define BB 2
#define LL 1024
#define DI 1536
#define DS 16
#define TPB 256
#define NC 64
#define CL (LL / NC)   // 16

#define LOG2E 1.44269504088896340736f

__device__ __forceinline__ float exp2_fast(float x) { return __builtin_amdgcn_exp2f(x); }

// ---------------------------------------------------------------------------
// Pass 1: thread <-> (b, d, chunk); all 16 n-states in registers.
// B tile [CL][16] staged via LDS (one coalesced load); per-step B access is an
// all-lanes-same-address ds_read_b128 broadcast (no per-step global loads).
// Stores per-chunk: sdt = sum(delta) and Bacc[n]:
//   x_after = exp2(Av2[n]*sdt)*x_before + Bacc[n]
// Layouts: sdt [c][b][d], bsum [c][b][d][n] (n-minor; float4 I/O)
// ---------------------------------------------------------------------------
__global__ __launch_bounds__(TPB) void ss1(
    const float* __restrict__ u, const float* __restrict__ delta,
    const float* __restrict__ A, const float* __restrict__ Bm,
    float* __restrict__ sdt_out, float* __restrict__ bsum)
{
    __shared__ float bsh[CL * DS];

    const int tid = threadIdx.x;
    const int d = blockIdx.x * TPB + tid;
    const int c = blockIdx.y;
    const int b = blockIdx.z;

    const size_t bl0 = (size_t)b * LL + (size_t)c * CL;

    // Stage B tile: CL*DS = 256 consecutive floats, one coalesced load.
    {
        const float* __restrict__ bp0 = Bm + bl0 * DS;
        if (tid < CL * DS) bsh[tid] = bp0[tid];
    }

    float Av2[DS];
    {
        const float4* Ap = (const float4*)(A + (size_t)d * DS);
        #pragma unroll
        for (int q = 0; q < 4; ++q) {
            const float4 av = Ap[q];
            Av2[q*4+0] = av.x * LOG2E; Av2[q*4+1] = av.y * LOG2E;
            Av2[q*4+2] = av.z * LOG2E; Av2[q*4+3] = av.w * LOG2E;
        }
    }

    const float* __restrict__ dp = delta + bl0 * DI + d;
    const float* __restrict__ up = u     + bl0 * DI + d;

    float dt[CL], uu[CL];
    #pragma unroll
    for (int i = 0; i < CL; ++i) {
        dt[i] = dp[(size_t)i * DI];          // coalesced 256B/wave
        uu[i] = up[(size_t)i * DI];
    }

    __syncthreads();

    float Bacc[DS];
    #pragma unroll
    for (int n = 0; n < DS; ++n) Bacc[n] = 0.0f;
    float sdt = 0.0f;

    #pragma unroll
    for (int i = 0; i < CL; ++i) {
        const float du = dt[i] * uu[i];
        sdt += dt[i];
        const float4* bt4 = (const float4*)(bsh + i * DS);   // LDS broadcast
        const float4 b0 = bt4[0], b1 = bt4[1], b2 = bt4[2], b3 = bt4[3];
        const float bv[DS] = {b0.x,b0.y,b0.z,b0.w, b1.x,b1.y,b1.z,b1.w,
                              b2.x,b2.y,b2.z,b2.w, b3.x,b3.y,b3.z,b3.w};
        #pragma unroll
        for (int n = 0; n < DS; ++n) {
            const float a = exp2_fast(dt[i] * Av2[n]);
            Bacc[n] = fmaf(a, Bacc[n], du * bv[n]);
        }
    }

    sdt_out[((size_t)c * BB + b) * DI + d] = sdt;
    float4* __restrict__ sp = (float4*)(bsum + (((size_t)c * BB + b) * DI + d) * DS);
    #pragma unroll
    for (int q = 0; q < 4; ++q)
        sp[q] = make_float4(Bacc[q*4+0], Bacc[q*4+1], Bacc[q*4+2], Bacc[q*4+3]);
}

// ---------------------------------------------------------------------------
// Pass 1.5: exclusive scan over chunks per (b,d,n) chain.
// Prefetch-batched: 32 (sdt,bsum) pairs loaded into registers per half
// (independent, compile-time indexed), then folded — kills the 64-step
// load-latency chain.
// ---------------------------------------------------------------------------
__global__ __launch_bounds__(TPB) void ss_scan(
    const float* __restrict__ A,
    const float* __restrict__ sdt_in, const float* __restrict__ bsum,
    float* __restrict__ xin)
{
    const int gid = blockIdx.x * TPB + threadIdx.x;   // (b*DI+d)*DS+n
    const int bd  = gid >> 4;
    const int d   = bd % DI;
    const int n   = gid & 15;
    const float Av2 = A[d * DS + n] * LOG2E;

    const size_t cstr = (size_t)BB * DI * DS;
    const size_t sstr = (size_t)BB * DI;

    float x = 0.0f;
    #pragma unroll
    for (int half = 0; half < 2; ++half) {
        const int c0 = half * 32;
        float sd[32], bs[32];
        #pragma unroll
        for (int j = 0; j < 32; ++j) {
            sd[j] = sdt_in[(size_t)(c0 + j) * sstr + bd];
            bs[j] = bsum[(size_t)(c0 + j) * cstr + gid];
        }
        #pragma unroll
        for (int j = 0; j < 32; ++j) {
            xin[(size_t)(c0 + j) * cstr + gid] = x;     // state BEFORE chunk
            const float a = exp2_fast(Av2 * sd[j]);
            x = fmaf(a, x, bs[j]);
        }
    }
}

// ---------------------------------------------------------------------------
// Pass 2: thread <-> (b, d, chunk); B and C tiles staged via LDS; load
// incoming state (float4), re-run chunk, reduce over n in regs, write y.
// ---------------------------------------------------------------------------
__global__ __launch_bounds__(TPB) void ss2(
    const float* __restrict__ u, const float* __restrict__ delta,
    const float* __restrict__ A, const float* __restrict__ Bm,
    const float* __restrict__ Cm, const float* __restrict__ Dv,
    const float* __restrict__ xin, float* __restrict__ y)
{
    __shared__ float bsh[CL * DS];
    __shared__ float csh[CL * DS];

    const int tid = threadIdx.x;
    const int d = blockIdx.x * TPB + tid;
    const int c = blockIdx.y;
    const int b = blockIdx.z;

    const size_t bl0 = (size_t)b * LL + (size_t)c * CL;

    // Stage B and C tiles (one coalesced load each).
    {
        const float* __restrict__ bp0 = Bm + bl0 * DS;
        const float* __restrict__ cp0 = Cm + bl0 * DS;
        if (tid < CL * DS) {
            bsh[tid] = bp0[tid];
            csh[tid] = cp0[tid];
        }
    }

    float Av2[DS];
    {
        const float4* Ap = (const float4*)(A + (size_t)d * DS);
        #pragma unroll
        for (int q = 0; q < 4; ++q) {
            const float4 av = Ap[q];
            Av2[q*4+0] = av.x * LOG2E; Av2[q*4+1] = av.y * LOG2E;
            Av2[q*4+2] = av.z * LOG2E; Av2[q*4+3] = av.w * LOG2E;
        }
    }

    float x[DS];
    {
        const float4* __restrict__ xp =
            (const float4*)(xin + (((size_t)c * BB + b) * DI + d) * DS);
        #pragma unroll
        for (int q = 0; q < 4; ++q) {
            const float4 v = xp[q];
            x[q*4+0] = v.x; x[q*4+1] = v.y; x[q*4+2] = v.z; x[q*4+3] = v.w;
        }
    }

    const float Dd = Dv[d];

    const float* __restrict__ dp = delta + bl0 * DI + d;
    const float* __restrict__ up = u     + bl0 * DI + d;
    float* __restrict__ yp       = y     + bl0 * DI + d;

    float dt[CL], uu[CL];
    #pragma unroll
    for (int i = 0; i < CL; ++i) {
        dt[i] = dp[(size_t)i * DI];
        uu[i] = up[(size_t)i * DI];
    }

    __syncthreads();

    #pragma unroll
    for (int i = 0; i < CL; ++i) {
        const float du = dt[i] * uu[i];
        const float4* bt4 = (const float4*)(bsh + i * DS);   // LDS broadcast
        const float4* ct4 = (const float4*)(csh + i * DS);
        const float4 b0 = bt4[0], b1 = bt4[1], b2 = bt4[2], b3 = bt4[3];
        const float4 c0 = ct4[0], c1 = ct4[1], c2 = ct4[2], c3 = ct4[3];
        const float bv[DS] = {b0.x,b0.y,b0.z,b0.w, b1.x,b1.y,b1.z,b1.w,
                              b2.x,b2.y,b2.z,b2.w, b3.x,b3.y,b3.z,b3.w};
        const float cv[DS] = {c0.x,c0.y,c0.z,c0.w, c1.x,c1.y,c1.z,c1.w,
                              c2.x,c2.y,c2.z,c2.w, c3.x,c3.y,c3.z,c3.w};
        float y0 = 0.0f, y1 = 0.0f;
        #pragma unroll
        for (int n = 0; n < DS; ++n) {
            const float a = exp2_fast(dt[i] * Av2[n]);
            x[n] = fmaf(a, x[n], du * bv[n]);
            if (n & 1) y1 = fmaf(x[n], cv[n], y1);
            else       y0 = fmaf(x[n], cv[n], y0);
        }
        yp[(size_t)i * DI] = fmaf(uu[i], Dd, y0 + y1);
    }
}

// Fallback: streaming serial scan (no workspace needed)
__global__ __launch_bounds__(TPB) void ss_serial(
    const float* __restrict__ u, const float* __restrict__ delta,
    const float* __restrict__ A, const float* __restrict__ Bm,
    const float* __restrict__ Cm, const float* __restrict__ Dv,
    float* __restrict__ y)
{
    const int d = blockIdx.x * TPB + threadIdx.x;
    const int b = blockIdx.z;

    float Av2[DS];
    #pragma unroll
    for (int n = 0; n < DS; ++n) Av2[n] = A[d * DS + n] * LOG2E;

    float x[DS];
    #pragma unroll
    for (int n = 0; n < DS; ++n) x[n] = 0.0f;

    const float Dd = Dv[d];
    const size_t bl0 = (size_t)b * LL;
    const float* __restrict__ dp = delta + bl0 * DI + d;
    const float* __restrict__ up = u     + bl0 * DI + d;
    const float* __restrict__ bp = Bm    + bl0 * DS;
    const float* __restrict__ cp = Cm    + bl0 * DS;
    float* __restrict__ yp       = y     + bl0 * DI + d;

    for (int t = 0; t < LL; ++t) {
        const float dtv = dp[(size_t)t * DI];
        const float uuv = up[(size_t)t * DI];
        const float du = dtv * uuv;
        const float* __restrict__ bt = bp + t * DS;
        const float* __restrict__ ct = cp + t * DS;
        float y0 = 0.0f, y1 = 0.0f;
        #pragma unroll
        for (int n = 0; n < DS; ++n) {
            const float a = exp2_fast(dtv * Av2[n]);
            x[n] = fmaf(a, x[n], du * bt[n]);
            if (n & 1) y1 = fmaf(x[n], ct[n], y1);
            else       y0 = fmaf(x[n], ct[n], y0);
        }
        yp[(size_t)t * DI] = fmaf(uuv, Dd, y0 + y1);
    }
}

extern "C" void kernel_launch(void* const* d_in, const int* in_sizes, int n_in,
                              void* d_out, int out_size, void* d_ws, size_t ws_size,
                              hipStream_t stream) {
    const float* u     = (const float*)d_in[0];
    const float* delta = (const float*)d_in[1];
    const float* A     = (const float*)d_in[2];
    const float* Bm    = (const float*)d_in[3];
    const float* Cm    = (const float*)d_in[4];
    const float* Dv    = (const float*)d_in[5];
    float* y = (float*)d_out;

    const size_t sdt_bytes  = (size_t)NC * BB * DI * sizeof(float);        // 0.8 MB
    const size_t bsum_bytes = (size_t)NC * BB * DI * DS * sizeof(float);   // 12.6 MB

    if (ws_size >= sdt_bytes + 2 * bsum_bytes) {
        float* sdt  = (float*)d_ws;
        float* bsum = (float*)((char*)d_ws + sdt_bytes);
        float* xin  = (float*)((char*)d_ws + sdt_bytes + bsum_bytes);

        dim3 grid1(DI / TPB, NC, BB);
        ss1<<<grid1, TPB, 0, stream>>>(u, delta, A, Bm, sdt, bsum);

        dim3 gridS((BB * DI * DS) / TPB, 1, 1);
        ss_scan<<<gridS, TPB, 0, stream>>>(A, sdt, bsum, xin);

        ss2<<<grid1, TPB, 0, stream>>>(u, delta, A, Bm, Cm, Dv, xin, y);
    } else {
        dim3 grid(DI / TPB, 1, BB);
        ss_serial<<<grid, TPB, 0, stream>>>(u, delta, A, Bm, Cm, Dv, y);
    }
}